// Round 11
// baseline (134.163 us; speedup 1.0000x reference)
//
#include <hip/hip_runtime.h>
#include <hip/hip_bf16.h>
#include <math.h>

#define B 32
#define S 8
#define FEA 2560
#define T 800
#define NCL 512
#define EMB 256
#define H 8

#define BF 64            // features per block (16 per wave)
#define SEC 128          // k-floats per staged section
#define NSEC 6           // full sections (k 0..767); tail 32 via direct-global MFMA
#define WVB 4096         // bytes per wave x-buffer: 16 rows * 256 B

typedef __attribute__((ext_vector_type(8))) short bf16x8;
typedef __attribute__((ext_vector_type(4))) float f32x4;

__device__ __forceinline__ short4 cvt_bf16x4(float4 v) {
    union { short4 s4; __hip_bfloat162 h[2]; } u;
    u.h[0] = __float22bfloat162_rn(make_float2(v.x, v.y));
    u.h[1] = __float22bfloat162_rn(make_float2(v.z, v.w));
    return u.s4;
}

// ---- wave-private x staging: 16 rows x 128 k per section; 2 rows x 512 B runs per instr ----
__device__ __forceinline__ void load_sec_w(const float* __restrict__ xw, int sec,
                                           int lane, float4 R[8]) {
    const int c4 = lane & 31;
    #pragma unroll
    for (int r = 0; r < 8; ++r) {
        const int row = r * 2 + (lane >> 5);
        R[r] = *(const float4*)(xw + (size_t)row * T + sec * SEC + c4 * 4);
    }
}

__device__ __forceinline__ void write_sec_w(char* __restrict__ buf, int lane, const float4 R[8]) {
    const int c4 = lane & 31;
    #pragma unroll
    for (int r = 0; r < 8; ++r) {
        const int row = r * 2 + (lane >> 5);
        *(short4*)(buf + row * 256 + ((c4 * 8) ^ ((row & 7) << 4))) = cvt_bf16x4(R[r]);
    }
}

// ---- mask A-fragments for one section straight from global (L2-hot) ----
__device__ __forceinline__ void load_mfrag(const float* __restrict__ mrow, int sec,
                                           int kb, bf16x8 M[4]) {
    #pragma unroll
    for (int st = 0; st < 4; ++st) {
        const float* p = mrow + sec * SEC + st * 32 + kb * 8;
        const float4 m0 = *(const float4*)(p);
        const float4 m1 = *(const float4*)(p + 4);
        union { bf16x8 v; short4 s4[2]; } u;
        u.s4[0] = cvt_bf16x4(m0);
        u.s4[1] = cvt_bf16x4(m1);
        M[st] = u.v;
    }
}

// 4 MFMA steps over one staged section (K=128)
#define STEP4(bufp, M) {                                                             \
    _Pragma("unroll")                                                                \
    for (int st_ = 0; st_ < 4; ++st_) {                                              \
        const bf16x8 bx_ = *(const bf16x8*)((bufp) + xrow * 256                      \
                              + ((st_ * 64 + kb16) ^ xswz));                         \
        acc = __builtin_amdgcn_mfma_f32_16x16x32_bf16(M[st_], bx_, acc, 0, 0, 0);    \
    }                                                                                \
}

// ---------------- Kernel A: pooled via MFMA; wave-private, zero barriers ----------------
// grid (41, 32): x<40 pool tiles, x==40 & b<8 -> u blocks.
__global__ __launch_bounds__(256, 4) void pool_u_kernel(const float* __restrict__ x,
                                                        const float* __restrict__ mask,
                                                        const float* __restrict__ U_w,
                                                        const float* __restrict__ U_b,
                                                        const float* __restrict__ m,
                                                        float* __restrict__ pooled,
                                                        float* __restrict__ u_out) {
    const int b = blockIdx.y;

    if (blockIdx.x == FEA / BF) {
        if (b >= 8) return;
        const int n  = b * 64 + (threadIdx.x >> 2);
        const int h0 = (threadIdx.x & 3) * 2;
        float a0 = 0.f, a1 = 0.f;
        #pragma unroll 4
        for (int e = 0; e < EMB; ++e) {
            const float mv = m[n * EMB + e];
            a0 += mv * U_w[h0 * EMB + e];
            a1 += mv * U_w[(h0 + 1) * EMB + e];
        }
        u_out[n * H + h0]     = a0 + U_b[h0];
        u_out[n * H + h0 + 1] = a1 + U_b[h0 + 1];
        return;
    }

    __shared__ char xls[4 * 2 * WVB];          // 32768 B, wave-private double buffers

    const int tid  = threadIdx.x;
    const int wave = tid >> 6, lane = tid & 63;
    const int f0   = blockIdx.x * BF;

    const int kb16 = (lane >> 4) * 16;         // byte offset of k-subblock in a 32k step
    const int kb   = lane >> 4;
    const int xrow = lane & 15;
    const int xswz = (xrow & 7) << 4;
    const int srow = lane & 7;

    const float* xw   = x + ((size_t)b * FEA + f0 + wave * 16) * T;
    const float* mrow = mask + ((size_t)(b * S + srow)) * T;
    char* buf0 = xls + wave * 2 * WVB;
    char* buf1 = buf0 + WVB;

    float4 R0[8], R1[8];
    bf16x8 Ma[4], Mb[4];

    // ---- prologue ----
    load_sec_w(xw, 0, lane, R0);
    load_sec_w(xw, 1, lane, R1);
    load_mfrag(mrow, 0, kb, Ma);
    write_sec_w(buf0, lane, R0);          // sec 0 -> buf0
    load_sec_w(xw, 2, lane, R0);
    write_sec_w(buf1, lane, R1);          // sec 1 -> buf1
    load_sec_w(xw, 3, lane, R1);

    f32x4 acc = {0.f, 0.f, 0.f, 0.f};

    // ---- main loop: zero barriers; x writes lag their loads by a full iteration ----
    #pragma unroll 1
    for (int st = 0; st < NSEC; st += 2) {
        load_mfrag(mrow, st + 1, kb, Mb);         // next-section mask (L2)
        STEP4(buf0, Ma)                           // sec st
        if (st + 2 < NSEC) {
            write_sec_w(buf0, lane, R0);          // sec st+2 (R0 loaded last iter)
            if (st + 4 < NSEC) load_sec_w(xw, st + 4, lane, R0);
            load_mfrag(mrow, st + 2, kb, Ma);
        }
        STEP4(buf1, Mb)                           // sec st+1
        if (st + 3 < NSEC) {
            write_sec_w(buf1, lane, R1);          // sec st+3
            if (st + 5 < NSEC) load_sec_w(xw, st + 5, lane, R1);
        }
    }

    // ---- tail: k 768..799 — x and mask straight from global ----
    {
        const float* xt = xw + (size_t)xrow * T + 768 + kb * 8;
        const float4 t0 = *(const float4*)(xt);
        const float4 t1 = *(const float4*)(xt + 4);
        union { bf16x8 v; short4 s4[2]; } Bx;
        Bx.s4[0] = cvt_bf16x4(t0);
        Bx.s4[1] = cvt_bf16x4(t1);
        const float* mp = mrow + 768 + kb * 8;
        union { bf16x8 v; short4 s4[2]; } Am;
        Am.s4[0] = cvt_bf16x4(*(const float4*)(mp));
        Am.s4[1] = cvt_bf16x4(*(const float4*)(mp + 4));
        acc = __builtin_amdgcn_mfma_f32_16x16x32_bf16(Am.v, Bx.v, acc, 0, 0, 0);
    }

    // C/D layout: col = lane&15, row = (lane>>4)*4 + i. Rows 0..7 = speakers.
    if (lane < 32) {
        const int col = lane & 15;
        #pragma unroll
        for (int i = 0; i < 4; ++i) {
            const int sr = (lane >> 4) * 4 + i;
            pooled[(size_t)(b * S + sr) * FEA + f0 + wave * 16 + col] = acc[i];
        }
    }
}

// ---------------- Kernel B1: per (b,s) denom + w (+ zero out for the atomics) ----------------
__global__ __launch_bounds__(256) void wden_kernel(const float* __restrict__ pooled,
                                                   const float* __restrict__ mask,
                                                   const float* __restrict__ W_w,
                                                   const float* __restrict__ W_b,
                                                   float* __restrict__ w_out,
                                                   float* __restrict__ out) {
    __shared__ float red[256];
    __shared__ float wred[4][8];
    const int bs  = blockIdx.x;
    const int tid = threadIdx.x;

    out[bs * EMB + tid] = 0.f;   // EMB == 256 == blockDim.x

    float p = 0.f;
    for (int t = tid; t < T; t += 256) p += mask[(size_t)bs * T + t];
    red[tid] = p;
    __syncthreads();
    for (int st = 128; st > 0; st >>= 1) {
        if (tid < st) red[tid] += red[tid + st];
        __syncthreads();
    }
    const float inv_d = 1.f / (red[0] + 1e-10f);

    float acc[8];
    #pragma unroll
    for (int h = 0; h < 8; ++h) acc[h] = 0.f;
    for (int f = tid; f < FEA; f += 256) {
        const float xv = pooled[(size_t)bs * FEA + f] * inv_d;
        #pragma unroll
        for (int h = 0; h < 8; ++h) acc[h] += xv * W_w[h * FEA + f];
    }
    const int lane = tid & 63, wave = tid >> 6;
    #pragma unroll
    for (int h = 0; h < 8; ++h) {
        float v = acc[h];
        #pragma unroll
        for (int off = 32; off > 0; off >>= 1) v += __shfl_xor(v, off, 64);
        if (lane == 0) wred[wave][h] = v;
    }
    __syncthreads();
    if (tid < 8)
        w_out[bs * H + tid] = wred[0][tid] + wred[1][tid] + wred[2][tid] + wred[3][tid] + W_b[tid];
}

// ---------------- Kernel B2: fused gate + e = a @ m (n-split, atomic accumulate) ----------------
__global__ __launch_bounds__(256) void egemv_kernel(const float* __restrict__ w_buf,
                                                    const float* __restrict__ u_buf,
                                                    const float* __restrict__ v_w,
                                                    const float* __restrict__ v_b,
                                                    const float* __restrict__ m,
                                                    float* __restrict__ out) {
    __shared__ float a_sh[256];
    const int bs = blockIdx.x >> 1, half = blockIdx.x & 1;
    const int tid = threadIdx.x;
    const int n = half * 256 + tid;

    float c = v_b[0];
    #pragma unroll
    for (int h = 0; h < 8; ++h)
        c += tanhf(w_buf[bs * H + h] + u_buf[n * H + h]) * v_w[h];
    a_sh[tid] = 1.f / (1.f + expf(-c));
    __syncthreads();

    float acc = 0.f;
    #pragma unroll 8
    for (int n2 = 0; n2 < 256; ++n2)
        acc += a_sh[n2] * m[(half * 256 + n2) * EMB + tid];
    atomicAdd(&out[bs * EMB + tid], acc);
}

extern "C" void kernel_launch(void* const* d_in, const int* in_sizes, int n_in,
                              void* d_out, int out_size, void* d_ws, size_t ws_size,
                              hipStream_t stream) {
    const float* x    = (const float*)d_in[0];
    const float* mask = (const float*)d_in[1];
    const float* W_w  = (const float*)d_in[2];
    const float* W_b  = (const float*)d_in[3];
    const float* U_w  = (const float*)d_in[4];
    const float* U_b  = (const float*)d_in[5];
    const float* v_w  = (const float*)d_in[6];
    const float* v_b  = (const float*)d_in[7];
    const float* m    = (const float*)d_in[8];
    float* out = (float*)d_out;

    float* ws     = (float*)d_ws;
    float* pooled = ws;                          // B*S*FEA
    float* u_buf  = pooled + B * S * FEA;        // NCL*H
    float* w_buf  = u_buf + NCL * H;             // B*S*H

    pool_u_kernel<<<dim3(FEA / BF + 1, B), 256, 0, stream>>>(
        x, mask, U_w, U_b, m, pooled, u_buf);
    wden_kernel<<<B * S, 256, 0, stream>>>(pooled, mask, W_w, W_b, w_buf, out);
    egemv_kernel<<<B * S * 2, 256, 0, stream>>>(w_buf, u_buf, v_w, v_b, m, out);
}

// Round 12
// 75.994 us; speedup vs baseline: 1.7655x; 1.7655x over previous
//
#include <hip/hip_runtime.h>
#include <hip/hip_bf16.h>
#include <math.h>

#define B 32
#define S 8
#define FEA 2560
#define T 800
#define NCL 512
#define EMB 256
#define H 8

#define BF 64            // features per block (16 per wave)
#define PAIRB 256        // k floats per staged pair (two 128-float sections)
#define XHALF 16384      // bytes per half buffer: 64 rows * 256 B
#define MROWB 1664       // bytes per mask row in LDS (1600 data + 64 pad)

typedef __attribute__((ext_vector_type(8))) short bf16x8;
typedef __attribute__((ext_vector_type(4))) float f32x4;

__device__ __forceinline__ short4 cvt_bf16x4(float4 v) {
    union { short4 s4; __hip_bfloat162 h[2]; } u;
    u.h[0] = __float22bfloat162_rn(make_float2(v.x, v.y));
    u.h[1] = __float22bfloat162_rn(make_float2(v.z, v.w));
    return u.s4;
}

// Stage loads: thread covers rows r*4+lrow, cols [lc4, lc4+4) of the 256-float pair
// window -> each wave instruction = ONE row x 1024 B contiguous.
#define LOAD_PAIR(p) {                                                              \
    _Pragma("unroll")                                                               \
    for (int r = 0; r < 16; ++r)                                                    \
        R[r] = *(const float4*)(xb + (size_t)(f0 + r * 4 + lrow) * T                \
                                + (p) * PAIRB + lc4);                               \
}

// Write pair to LDS: cols 0-127 -> half0, 128-255 -> half1; XOR swizzle per row.
#define WRITE_PAIR() {                                                              \
    _Pragma("unroll")                                                               \
    for (int r = 0; r < 16; ++r) {                                                  \
        const int row_ = r * 4 + lrow;                                              \
        *(short4*)(xls + whalf * XHALF + row_ * 256 + (wb8 ^ ((row_ & 7) << 4)))    \
            = cvt_bf16x4(R[r]);                                                     \
    }                                                                               \
}

// One MFMA step (32 k) of pair p, step st in 0..7 (st>>2 selects half).
#define CSTEP(p, st) {                                                              \
    const bf16x8 bx_ = *(const bf16x8*)(xls + ((st) >> 2) * XHALF + xrow * 256      \
                          + ((((st) & 3) * 64 + kb16) ^ xswz));                     \
    const bf16x8 am_ = *(const bf16x8*)((const char*)mask_l + mbase                 \
                          + ((((p) * 8 + (st)) * 64 + kb16) ^ mswz));               \
    acc = __builtin_amdgcn_mfma_f32_16x16x32_bf16(am_, bx_, acc, 0, 0, 0);          \
}

#define CPAIR(p) { CSTEP(p,0) CSTEP(p,1) CSTEP(p,2) CSTEP(p,3)                      \
                   CSTEP(p,4) CSTEP(p,5) CSTEP(p,6) CSTEP(p,7) }

// ---------------- Kernel A: pooled via MFMA; 1KB-run staging, pair pipeline ----------------
// grid (41, 32): x<40 pool tiles, x==40 & b<8 -> u blocks.
__global__ __launch_bounds__(256) void pool_u_kernel(const float* __restrict__ x,
                                                     const float* __restrict__ mask,
                                                     const float* __restrict__ U_w,
                                                     const float* __restrict__ U_b,
                                                     const float* __restrict__ m,
                                                     float* __restrict__ pooled,
                                                     float* __restrict__ u_out) {
    const int b = blockIdx.y;

    if (blockIdx.x == FEA / BF) {
        if (b >= 8) return;
        const int n  = b * 64 + (threadIdx.x >> 2);
        const int h0 = (threadIdx.x & 3) * 2;
        float a0 = 0.f, a1 = 0.f;
        #pragma unroll 4
        for (int e = 0; e < EMB; ++e) {
            const float mv = m[n * EMB + e];
            a0 += mv * U_w[h0 * EMB + e];
            a1 += mv * U_w[(h0 + 1) * EMB + e];
        }
        u_out[n * H + h0]     = a0 + U_b[h0];
        u_out[n * H + h0 + 1] = a1 + U_b[h0 + 1];
        return;
    }

    __shared__ short mask_l[S * (MROWB / 2)];   // 13312 B
    __shared__ char  xls[2 * XHALF];            // 32768 B (one pair: half0 + half1)

    const int tid = threadIdx.x;
    const int f0  = blockIdx.x * BF;
    const float* xb = x + (size_t)b * FEA * T;

    // staging mapping
    const int lrow = tid >> 6;              // row offset within each 4-row group
    const int lc4  = (tid & 63) * 4;        // col floats [lc4, lc4+4)
    const int whalf = (tid & 63) >> 5;      // 0: cols 0-127, 1: 128-255
    const int wb8   = (tid & 31) * 8;       // byte offset within half row

    float4 R[16];

    // ---- prologue: issue pair-0 loads; stage mask while they fly ----
    LOAD_PAIR(0)

    for (int v = tid; v < S * 200; v += 256) {
        const int s = v / 200, c4 = v % 200;
        const float4 mv = *(const float4*)(mask + ((size_t)(b * S + s)) * T + c4 * 4);
        const int byte = s * MROWB + ((c4 * 8) ^ (s << 4));
        *(short4*)((char*)mask_l + byte) = cvt_bf16x4(mv);
    }

    WRITE_PAIR()             // pair 0 -> LDS (compiler waits vmcnt for R)
    LOAD_PAIR(1)             // flies across the barrier + pair-0 compute
    __syncthreads();         // mask + pair 0 visible

    // compute-side mapping
    const int wave = tid >> 6, lane = tid & 63;
    const int kb16 = (lane >> 4) * 16;
    const int xrow = wave * 16 + (lane & 15);
    const int xswz = (xrow & 7) << 4;
    const int srow = lane & 7;
    const int mbase = srow * MROWB;
    const int mswz = srow << 4;

    f32x4 acc = {0.f, 0.f, 0.f, 0.f};

    // ---- pair 0 ----
    CPAIR(0)
    __syncthreads();         // all reads of pair 0 done (drains pair-1 loads)
    WRITE_PAIR()             // pair 1 -> LDS
    LOAD_PAIR(2)             // flies across barrier + pair-1 compute
    __syncthreads();         // pair 1 visible

    // ---- pair 1 ----
    CPAIR(1)
    __syncthreads();
    WRITE_PAIR()             // pair 2 -> LDS
    __syncthreads();

    // ---- pair 2 ----
    CPAIR(2)

    // ---- tail: k 768..799 — x direct from global, mask from LDS (kstep = 24) ----
    {
        const float* xt = xb + (size_t)(f0 + xrow) * T + 768 + (lane >> 4) * 8;
        const float4 t0 = *(const float4*)(xt);
        const float4 t1 = *(const float4*)(xt + 4);
        union { bf16x8 v; short4 s4[2]; } Bx;
        Bx.s4[0] = cvt_bf16x4(t0);
        Bx.s4[1] = cvt_bf16x4(t1);
        const bf16x8 am = *(const bf16x8*)((const char*)mask_l + mbase
                              + ((24 * 64 + kb16) ^ mswz));
        acc = __builtin_amdgcn_mfma_f32_16x16x32_bf16(am, Bx.v, acc, 0, 0, 0);
    }

    // C/D layout: col = lane&15, row = (lane>>4)*4 + i. Rows 0..7 = speakers.
    if (lane < 32) {
        const int col = lane & 15;
        #pragma unroll
        for (int i = 0; i < 4; ++i) {
            const int sr = (lane >> 4) * 4 + i;
            pooled[(size_t)(b * S + sr) * FEA + f0 + wave * 16 + col] = acc[i];
        }
    }
}

// ---------------- Kernel B1: per (b,s) denom + w (+ zero out for the atomics) ----------------
__global__ __launch_bounds__(256) void wden_kernel(const float* __restrict__ pooled,
                                                   const float* __restrict__ mask,
                                                   const float* __restrict__ W_w,
                                                   const float* __restrict__ W_b,
                                                   float* __restrict__ w_out,
                                                   float* __restrict__ out) {
    __shared__ float red[256];
    __shared__ float wred[4][8];
    const int bs  = blockIdx.x;
    const int tid = threadIdx.x;

    out[bs * EMB + tid] = 0.f;   // EMB == 256 == blockDim.x

    float p = 0.f;
    for (int t = tid; t < T; t += 256) p += mask[(size_t)bs * T + t];
    red[tid] = p;
    __syncthreads();
    for (int st = 128; st > 0; st >>= 1) {
        if (tid < st) red[tid] += red[tid + st];
        __syncthreads();
    }
    const float inv_d = 1.f / (red[0] + 1e-10f);

    float acc[8];
    #pragma unroll
    for (int h = 0; h < 8; ++h) acc[h] = 0.f;
    for (int f = tid; f < FEA; f += 256) {
        const float xv = pooled[(size_t)bs * FEA + f] * inv_d;
        #pragma unroll
        for (int h = 0; h < 8; ++h) acc[h] += xv * W_w[h * FEA + f];
    }
    const int lane = tid & 63, wave = tid >> 6;
    #pragma unroll
    for (int h = 0; h < 8; ++h) {
        float v = acc[h];
        #pragma unroll
        for (int off = 32; off > 0; off >>= 1) v += __shfl_xor(v, off, 64);
        if (lane == 0) wred[wave][h] = v;
    }
    __syncthreads();
    if (tid < 8)
        w_out[bs * H + tid] = wred[0][tid] + wred[1][tid] + wred[2][tid] + wred[3][tid] + W_b[tid];
}

// ---------------- Kernel B2: fused gate + e = a @ m (n-split, atomic accumulate) ----------------
__global__ __launch_bounds__(256) void egemv_kernel(const float* __restrict__ w_buf,
                                                    const float* __restrict__ u_buf,
                                                    const float* __restrict__ v_w,
                                                    const float* __restrict__ v_b,
                                                    const float* __restrict__ m,
                                                    float* __restrict__ out) {
    __shared__ float a_sh[256];
    const int bs = blockIdx.x >> 1, half = blockIdx.x & 1;
    const int tid = threadIdx.x;
    const int n = half * 256 + tid;

    float c = v_b[0];
    #pragma unroll
    for (int h = 0; h < 8; ++h)
        c += tanhf(w_buf[bs * H + h] + u_buf[n * H + h]) * v_w[h];
    a_sh[tid] = 1.f / (1.f + expf(-c));
    __syncthreads();

    float acc = 0.f;
    #pragma unroll 8
    for (int n2 = 0; n2 < 256; ++n2)
        acc += a_sh[n2] * m[(half * 256 + n2) * EMB + tid];
    atomicAdd(&out[bs * EMB + tid], acc);
}

extern "C" void kernel_launch(void* const* d_in, const int* in_sizes, int n_in,
                              void* d_out, int out_size, void* d_ws, size_t ws_size,
                              hipStream_t stream) {
    const float* x    = (const float*)d_in[0];
    const float* mask = (const float*)d_in[1];
    const float* W_w  = (const float*)d_in[2];
    const float* W_b  = (const float*)d_in[3];
    const float* U_w  = (const float*)d_in[4];
    const float* U_b  = (const float*)d_in[5];
    const float* v_w  = (const float*)d_in[6];
    const float* v_b  = (const float*)d_in[7];
    const float* m    = (const float*)d_in[8];
    float* out = (float*)d_out;

    float* ws     = (float*)d_ws;
    float* pooled = ws;                          // B*S*FEA
    float* u_buf  = pooled + B * S * FEA;        // NCL*H
    float* w_buf  = u_buf + NCL * H;             // B*S*H

    pool_u_kernel<<<dim3(FEA / BF + 1, B), 256, 0, stream>>>(
        x, mask, U_w, U_b, m, pooled, u_buf);
    wden_kernel<<<B * S, 256, 0, stream>>>(pooled, mask, W_w, W_b, w_buf, out);
    egemv_kernel<<<B * S * 2, 256, 0, stream>>>(w_buf, u_buf, v_w, v_b, m, out);
}

// Round 13
// 74.430 us; speedup vs baseline: 1.8025x; 1.0210x over previous
//
#include <hip/hip_runtime.h>
#include <hip/hip_bf16.h>
#include <math.h>

#define B 32
#define S 8
#define FEA 2560
#define T 800
#define NCL 512
#define EMB 256
#define H 8

#define BF 64            // features per block (16 per wave)
#define SEC 128          // k floats per staged section
#define NSEC 6           // full sections (k 0..767); tail 32 via direct-global MFMA
#define MROWB 1664       // bytes per mask row in LDS (1600 data + 64 pad)

typedef __attribute__((ext_vector_type(8))) short bf16x8;
typedef __attribute__((ext_vector_type(4))) float f32x4;

__device__ __forceinline__ short4 cvt_bf16x4(float4 v) {
    union { short4 s4; __hip_bfloat162 h[2]; } u;
    u.h[0] = __float22bfloat162_rn(make_float2(v.x, v.y));
    u.h[1] = __float22bfloat162_rn(make_float2(v.z, v.w));
    return u.s4;
}

// Stage: thread covers rows r*8+(tid>>5), cols [(tid&31)*4, +4) of the 128-float
// section window -> each wave instruction = 8 rows x 512 B contiguous runs.
#define LOAD_SEC(s) {                                                               \
    _Pragma("unroll")                                                               \
    for (int r = 0; r < 8; ++r)                                                     \
        R[r] = *(const float4*)(xb + (size_t)(f0 + r * 8 + (tid >> 5)) * T          \
                                + (s) * SEC + (tid & 31) * 4);                      \
}

#define WRITE_SEC() {                                                               \
    _Pragma("unroll")                                                               \
    for (int r = 0; r < 8; ++r) {                                                   \
        const int row_ = r * 8 + (tid >> 5);                                        \
        *(short4*)(xls + row_ * 256 + (((tid & 31) * 8) ^ ((row_ & 7) << 4)))       \
            = cvt_bf16x4(R[r]);                                                     \
    }                                                                               \
}

// One MFMA step (32 k) of section sec, step st in 0..3.
#define CSTEP(sec, st) {                                                            \
    const bf16x8 bx_ = *(const bf16x8*)(xls + xrow * 256                            \
                          + ((((st) & 3) * 64 + kb16) ^ xswz));                     \
    const bf16x8 am_ = *(const bf16x8*)((const char*)mask_l + mbase                 \
                          + ((((sec) * 4 + (st)) * 64 + kb16) ^ mswz));             \
    acc = __builtin_amdgcn_mfma_f32_16x16x32_bf16(am_, bx_, acc, 0, 0, 0);          \
}

#define CSEC(sec) { CSTEP(sec,0) CSTEP(sec,1) CSTEP(sec,2) CSTEP(sec,3) }

// ---------------- Kernel A: pooled via MFMA; 5 blocks/CU, single x-buffer ----------------
// grid (41, 32): x<40 pool tiles, x==40 & b<8 -> u blocks.
__global__ __launch_bounds__(256, 5) void pool_u_kernel(const float* __restrict__ x,
                                                        const float* __restrict__ mask,
                                                        const float* __restrict__ U_w,
                                                        const float* __restrict__ U_b,
                                                        const float* __restrict__ m,
                                                        float* __restrict__ pooled,
                                                        float* __restrict__ u_out) {
    const int b = blockIdx.y;

    if (blockIdx.x == FEA / BF) {
        if (b >= 8) return;
        const int n  = b * 64 + (threadIdx.x >> 2);
        const int h0 = (threadIdx.x & 3) * 2;
        float a0 = 0.f, a1 = 0.f;
        #pragma unroll 4
        for (int e = 0; e < EMB; ++e) {
            const float mv = m[n * EMB + e];
            a0 += mv * U_w[h0 * EMB + e];
            a1 += mv * U_w[(h0 + 1) * EMB + e];
        }
        u_out[n * H + h0]     = a0 + U_b[h0];
        u_out[n * H + h0 + 1] = a1 + U_b[h0 + 1];
        return;
    }

    __shared__ short mask_l[S * (MROWB / 2)];   // 13312 B
    __shared__ char  xls[16384];                // single 64-row x 256 B section buffer

    const int tid = threadIdx.x;
    const int f0  = blockIdx.x * BF;
    const float* xb = x + (size_t)b * FEA * T;

    float4 R[8];

    // ---- prologue: issue sec-0 loads; stage mask while they fly ----
    LOAD_SEC(0)

    for (int v = tid; v < S * 200; v += 256) {
        const int s = v / 200, c4 = v % 200;
        const float4 mv = *(const float4*)(mask + ((size_t)(b * S + s)) * T + c4 * 4);
        const int byte = s * MROWB + ((c4 * 8) ^ (s << 4));
        *(short4*)((char*)mask_l + byte) = cvt_bf16x4(mv);
    }

    WRITE_SEC()              // sec 0 -> LDS (vmcnt waits R only)
    LOAD_SEC(1)              // flies across barrier + sec-0 compute
    __syncthreads();         // mask + sec 0 visible

    // compute-side mapping
    const int wave = tid >> 6, lane = tid & 63;
    const int kb16 = (lane >> 4) * 16;
    const int xrow = wave * 16 + (lane & 15);
    const int xswz = (xrow & 7) << 4;
    const int srow = lane & 7;
    const int mbase = srow * MROWB;
    const int mswz = srow << 4;

    f32x4 acc = {0.f, 0.f, 0.f, 0.f};

    // ---- main loop: single buffer, 2 barriers/section, reg-prefetch one section ahead ----
    #pragma unroll 1
    for (int sec = 0; sec < NSEC; ++sec) {
        CSEC(sec)
        __syncthreads();                 // all reads of sec done
        if (sec < NSEC - 1) {
            WRITE_SEC()                  // sec+1 (R loaded one phase ago)
            if (sec < NSEC - 2) LOAD_SEC(sec + 2)
        }
        __syncthreads();                 // writes visible
    }

    // ---- tail: k 768..799 — x direct from global, mask from LDS (kstep = 24) ----
    {
        const float* xt = xb + (size_t)(f0 + xrow) * T + 768 + (lane >> 4) * 8;
        const float4 t0 = *(const float4*)(xt);
        const float4 t1 = *(const float4*)(xt + 4);
        union { bf16x8 v; short4 s4[2]; } Bx;
        Bx.s4[0] = cvt_bf16x4(t0);
        Bx.s4[1] = cvt_bf16x4(t1);
        const bf16x8 am = *(const bf16x8*)((const char*)mask_l + mbase
                              + ((24 * 64 + kb16) ^ mswz));
        acc = __builtin_amdgcn_mfma_f32_16x16x32_bf16(am, Bx.v, acc, 0, 0, 0);
    }

    // C/D layout: col = lane&15, row = (lane>>4)*4 + i. Rows 0..7 = speakers.
    if (lane < 32) {
        const int col = lane & 15;
        #pragma unroll
        for (int i = 0; i < 4; ++i) {
            const int sr = (lane >> 4) * 4 + i;
            pooled[(size_t)(b * S + sr) * FEA + f0 + wave * 16 + col] = acc[i];
        }
    }
}

// ---------------- Kernel B1: per (b,s) denom + w (+ zero out for the atomics) ----------------
__global__ __launch_bounds__(256) void wden_kernel(const float* __restrict__ pooled,
                                                   const float* __restrict__ mask,
                                                   const float* __restrict__ W_w,
                                                   const float* __restrict__ W_b,
                                                   float* __restrict__ w_out,
                                                   float* __restrict__ out) {
    __shared__ float red[256];
    __shared__ float wred[4][8];
    const int bs  = blockIdx.x;
    const int tid = threadIdx.x;

    out[bs * EMB + tid] = 0.f;   // EMB == 256 == blockDim.x

    float p = 0.f;
    for (int t = tid; t < T; t += 256) p += mask[(size_t)bs * T + t];
    red[tid] = p;
    __syncthreads();
    for (int st = 128; st > 0; st >>= 1) {
        if (tid < st) red[tid] += red[tid + st];
        __syncthreads();
    }
    const float inv_d = 1.f / (red[0] + 1e-10f);

    float acc[8];
    #pragma unroll
    for (int h = 0; h < 8; ++h) acc[h] = 0.f;
    for (int f = tid; f < FEA; f += 256) {
        const float xv = pooled[(size_t)bs * FEA + f] * inv_d;
        #pragma unroll
        for (int h = 0; h < 8; ++h) acc[h] += xv * W_w[h * FEA + f];
    }
    const int lane = tid & 63, wave = tid >> 6;
    #pragma unroll
    for (int h = 0; h < 8; ++h) {
        float v = acc[h];
        #pragma unroll
        for (int off = 32; off > 0; off >>= 1) v += __shfl_xor(v, off, 64);
        if (lane == 0) wred[wave][h] = v;
    }
    __syncthreads();
    if (tid < 8)
        w_out[bs * H + tid] = wred[0][tid] + wred[1][tid] + wred[2][tid] + wred[3][tid] + W_b[tid];
}

// ---------------- Kernel B2: fused gate + e = a @ m (n-split, atomic accumulate) ----------------
__global__ __launch_bounds__(256) void egemv_kernel(const float* __restrict__ w_buf,
                                                    const float* __restrict__ u_buf,
                                                    const float* __restrict__ v_w,
                                                    const float* __restrict__ v_b,
                                                    const float* __restrict__ m,
                                                    float* __restrict__ out) {
    __shared__ float a_sh[256];
    const int bs = blockIdx.x >> 1, half = blockIdx.x & 1;
    const int tid = threadIdx.x;
    const int n = half * 256 + tid;

    float c = v_b[0];
    #pragma unroll
    for (int h = 0; h < 8; ++h)
        c += tanhf(w_buf[bs * H + h] + u_buf[n * H + h]) * v_w[h];
    a_sh[tid] = 1.f / (1.f + expf(-c));
    __syncthreads();

    float acc = 0.f;
    #pragma unroll 8
    for (int n2 = 0; n2 < 256; ++n2)
        acc += a_sh[n2] * m[(half * 256 + n2) * EMB + tid];
    atomicAdd(&out[bs * EMB + tid], acc);
}

extern "C" void kernel_launch(void* const* d_in, const int* in_sizes, int n_in,
                              void* d_out, int out_size, void* d_ws, size_t ws_size,
                              hipStream_t stream) {
    const float* x    = (const float*)d_in[0];
    const float* mask = (const float*)d_in[1];
    const float* W_w  = (const float*)d_in[2];
    const float* W_b  = (const float*)d_in[3];
    const float* U_w  = (const float*)d_in[4];
    const float* U_b  = (const float*)d_in[5];
    const float* v_w  = (const float*)d_in[6];
    const float* v_b  = (const float*)d_in[7];
    const float* m    = (const float*)d_in[8];
    float* out = (float*)d_out;

    float* ws     = (float*)d_ws;
    float* pooled = ws;                          // B*S*FEA
    float* u_buf  = pooled + B * S * FEA;        // NCL*H
    float* w_buf  = u_buf + NCL * H;             // B*S*H

    pool_u_kernel<<<dim3(FEA / BF + 1, B), 256, 0, stream>>>(
        x, mask, U_w, U_b, m, pooled, u_buf);
    wden_kernel<<<B * S, 256, 0, stream>>>(pooled, mask, W_w, W_b, w_buf, out);
    egemv_kernel<<<B * S * 2, 256, 0, stream>>>(w_buf, u_buf, v_w, v_b, m, out);
}